// Round 3
// baseline (781.525 us; speedup 1.0000x reference)
//
#include <hip/hip_runtime.h>
#include <hip/hip_bf16.h>

using u16 = unsigned short;

#define DEVFN __device__ __forceinline__

static constexpr int Sn = 64*64*64;          // 262144 spatial per (b,c)
static constexpr float EPS_ = 1e-5f;

DEVFN float lo2f(unsigned int u){ union { unsigned int i; float f; } v; v.i = u << 16; return v.f; }
DEVFN float hi2f(unsigned int u){ union { unsigned int i; float f; } v; v.i = u & 0xffff0000u; return v.f; }
DEVFN float b2f(u16 u){ union { unsigned int i; float f; } v; v.i = ((unsigned int)u) << 16; return v.f; }
DEVFN u16 f2b(float f){
  union { float f; unsigned int i; } v; v.f = f;
  unsigned int r = v.i + 0x7fffu + ((v.i >> 16) & 1u);
  return (u16)(r >> 16);
}
DEVFN void unpack8(uint4 v, float* f){
  f[0]=lo2f(v.x); f[1]=hi2f(v.x);
  f[2]=lo2f(v.y); f[3]=hi2f(v.y);
  f[4]=lo2f(v.z); f[5]=hi2f(v.z);
  f[6]=lo2f(v.w); f[7]=hi2f(v.w);
}
DEVFN void load8f(const float* p, float* f){
  float4 a = *reinterpret_cast<const float4*>(p);
  float4 b = *reinterpret_cast<const float4*>(p + 4);
  f[0]=a.x; f[1]=a.y; f[2]=a.z; f[3]=a.w;
  f[4]=b.x; f[5]=b.y; f[6]=b.z; f[7]=b.w;
}

// ---------------- stats: partial sums per (b,c, quarter) ----------------
__global__ __launch_bounds__(256) void k_stats_partial(
    const float* __restrict__ x, float2* __restrict__ psum){
  int bid = blockIdx.x;            // 768 = 192 bc * 4 chunks
  int bc = bid >> 2, chunk = bid & 3;
  const float* p = x + (size_t)bc * Sn + (size_t)chunk * (Sn/4);
  float s = 0.f, s2 = 0.f;
  int t = threadIdx.x;
  #pragma unroll 4
  for (int k = 0; k < 32; ++k){
    float f[8]; load8f(p + (size_t)k*2048 + t*8, f);
    #pragma unroll
    for (int j=0;j<8;j++){ s += f[j]; s2 += f[j]*f[j]; }
  }
  #pragma unroll
  for (int off=32; off; off>>=1){ s += __shfl_down(s, off); s2 += __shfl_down(s2, off); }
  __shared__ float rs[4], rs2[4];
  int wid = t >> 6;
  if ((t & 63) == 0){ rs[wid]=s; rs2[wid]=s2; }
  __syncthreads();
  if (t == 0){
    psum[bid] = make_float2(rs[0]+rs[1]+rs[2]+rs[3], rs2[0]+rs2[1]+rs2[2]+rs2[3]);
  }
}

// ---------------- finalize stats + fold norm into in-proj weights ----------------
__global__ __launch_bounds__(192) void k_fold(
    const float2* __restrict__ psum,
    const float* __restrict__ gamma, const float* __restrict__ beta,
    const float* __restrict__ in_w, const float* __restrict__ in_b,
    float* __restrict__ W2t /* [b][c][o] f32 */, float* __restrict__ bias2 /* [b][o] */){
  __shared__ float scl[192], shf[192];
  int t = threadIdx.x;       // 0..191  ~ (b,c) and (b,o)
  {
    float s=0.f, s2=0.f;
    #pragma unroll
    for (int k=0;k<4;k++){ float2 v = psum[t*4+k]; s += v.x; s2 += v.y; }
    float inv = 1.f / (float)Sn;
    float mean = s * inv;
    float var  = s2 * inv - mean*mean;
    int c = t % 96;
    float sc = gamma[c] * rsqrtf(var + EPS_);
    scl[t] = sc;
    shf[t] = beta[c] - mean * sc;
  }
  __syncthreads();
  int b = t / 96, o = t % 96;
  float acc = in_b[o];
  for (int c=0;c<96;c++){
    float w = in_w[o*96 + c];
    int bc = b*96 + c;
    W2t[(size_t)bc*96 + o] = w * scl[bc];
    acc += w * shf[bc];
  }
  bias2[t] = acc;
}

// ---------------- GEMM in: xp[b][o][s] = sum_c W2[b][o][c]*x[b][c][s] + bias2 (fp32 out) ----------------
__global__ __launch_bounds__(192) void k_gemm_in(
    const float* __restrict__ x, const float* __restrict__ W2t,
    const float* __restrict__ bias2, float* __restrict__ xp){
  __shared__ float wt[96*96];   // [c][o] fp32
  int b = blockIdx.x >> 11;
  int s0 = (blockIdx.x & 2047) * 128;
  const float* wg = W2t + (size_t)b * 9216;
  for (int i = threadIdx.x; i < 9216; i += 192) wt[i] = wg[i];
  __syncthreads();
  int sgi = threadIdx.x & 15, ogi = threadIdx.x >> 4;   // 16 s-groups x 12 o-groups
  int o0 = ogi * 8;
  size_t sb = (size_t)b * (96ull*Sn) + (size_t)s0 + sgi*8;
  float acc[8][8];
  #pragma unroll
  for (int oi=0;oi<8;oi++){
    float bv = bias2[b*96 + o0 + oi];
    #pragma unroll
    for (int j=0;j<8;j++) acc[oi][j] = bv;
  }
  const float* xr = x + sb;
  for (int c=0;c<96;c++){
    float xf[8]; load8f(xr + (size_t)c*Sn, xf);
    float w[8];
    *reinterpret_cast<float4*>(&w[0]) = *reinterpret_cast<const float4*>(&wt[c*96+o0]);
    *reinterpret_cast<float4*>(&w[4]) = *reinterpret_cast<const float4*>(&wt[c*96+o0+4]);
    #pragma unroll
    for (int oi=0;oi<8;oi++){
      #pragma unroll
      for (int j=0;j<8;j++) acc[oi][j] = fmaf(w[oi], xf[j], acc[oi][j]);
    }
  }
  float* op = xp + sb;
  #pragma unroll
  for (int oi=0;oi<8;oi++){
    float* q = op + (size_t)(o0+oi)*Sn;
    *reinterpret_cast<float4*>(q)     = *reinterpret_cast<const float4*>(&acc[oi][0]);
    *reinterpret_cast<float4*>(q + 4) = *reinterpret_cast<const float4*>(&acc[oi][4]);
  }
}

// ---------------- depthwise 3x3x3 conv (+ optional SiLU), templated dtypes ----------------
template<int SILU, int IN32, int OUT32>
__global__ __launch_bounds__(256) void k_dw(
    const void* __restrict__ srcv, int sCPB, int sCOff,
    void* __restrict__ dstv, int dCPB, int dCOff,
    const float* __restrict__ wts /* [48][27] */, const float* __restrict__ bias){
  int id = blockIdx.x;                  // 2*48*64 blocks
  int d = id & 63; int c = (id >> 6) % 48; int b = id / (48*64);
  int t = threadIdx.x;
  int h = t >> 2, w0 = (t & 3) * 16;
  float wf[27];
  const float* wp = wts + c*27;
  #pragma unroll
  for (int k=0;k<27;k++) wf[k] = wp[k];
  float acc[16];
  float bv = bias[c];
  #pragma unroll
  for (int j=0;j<16;j++) acc[j] = bv;
  size_t cbase = ((size_t)(b*sCPB + sCOff + c)) * Sn;
  const float* spf = (const float*)srcv + cbase;
  const u16*   sph = (const u16*)srcv + cbase;
  #pragma unroll
  for (int dd=-1; dd<=1; dd++){
    int zd = d + dd; if (zd < 0 || zd > 63) continue;
    #pragma unroll
    for (int dh=-1; dh<=1; dh++){
      int zh = h + dh; if (zh < 0 || zh > 63) continue;
      int roff = zd*4096 + zh*64 + w0;
      float m[16], rl, rr;
      if (IN32){
        const float* row = spf + roff;
        load8f(row, m); load8f(row+8, m+8);
        rl = (w0 > 0)  ? row[-1] : 0.f;
        rr = (w0 < 48) ? row[16] : 0.f;
      } else {
        const u16* row = sph + roff;
        unpack8(*reinterpret_cast<const uint4*>(row), m);
        unpack8(*reinterpret_cast<const uint4*>(row+8), m+8);
        rl = (w0 > 0)  ? b2f(row[-1]) : 0.f;
        rr = (w0 < 48) ? b2f(row[16]) : 0.f;
      }
      const float* wk = &wf[(dd+1)*9 + (dh+1)*3];
      #pragma unroll
      for (int j=0;j<16;j++){
        float L = (j==0)  ? rl : m[j-1];
        float R = (j==15) ? rr : m[j+1];
        acc[j] += wk[0]*L + wk[1]*m[j] + wk[2]*R;
      }
    }
  }
  #pragma unroll
  for (int j=0;j<16;j++){
    float v = acc[j];
    if (SILU) v = v / (1.f + __expf(-v));
    acc[j] = v;
  }
  size_t doffs = ((size_t)(b*dCPB + dCOff + c)) * Sn + d*4096 + h*64 + w0;
  if (OUT32){
    float* dp = (float*)dstv + doffs;
    #pragma unroll
    for (int q=0;q<4;q++)
      *reinterpret_cast<float4*>(dp + q*4) = *reinterpret_cast<const float4*>(&acc[q*4]);
  } else {
    u16 ob[16];
    #pragma unroll
    for (int j=0;j<16;j++) ob[j] = f2b(acc[j]);
    u16* dp = (u16*)dstv + doffs;
    *reinterpret_cast<uint4*>(dp)   = *reinterpret_cast<const uint4*>(&ob[0]);
    *reinterpret_cast<uint4*>(dp+8) = *reinterpret_cast<const uint4*>(&ob[8]);
  }
}

// ---------------- GEMM out + residual (in-place on d_out, fp32) ----------------
__global__ __launch_bounds__(192) void k_gemm_out(
    const float* __restrict__ y1,   // d_out ch 0..47, fp32
    const u16* __restrict__ y2,    // ws, [b][48][S] bf16
    const float* __restrict__ x,   // residual (fp32)
    const float* __restrict__ ow, const float* __restrict__ obias,
    float* __restrict__ out){
  __shared__ float wt[96*96];     // [c][o]
  int b = blockIdx.x >> 11;
  int s0 = (blockIdx.x & 2047) * 128;
  for (int i = threadIdx.x; i < 9216; i += 192){
    int c = i / 96, o = i - c*96;
    wt[i] = ow[o*96 + c];         // transpose during stage (tiny, cached)
  }
  __syncthreads();
  int sgi = threadIdx.x & 15, ogi = threadIdx.x >> 4;
  int o0 = ogi * 8;
  size_t soff = (size_t)s0 + sgi*8;
  float acc[8][8];
  #pragma unroll
  for (int oi=0;oi<8;oi++){
    float bv = obias[o0+oi];
    #pragma unroll
    for (int j=0;j<8;j++) acc[oi][j] = bv;
  }
  const float* y1r = y1 + (size_t)b*96*Sn + soff;
  for (int c=0;c<48;c++){
    float xf[8]; load8f(y1r + (size_t)c*Sn, xf);
    float w[8];
    *reinterpret_cast<float4*>(&w[0]) = *reinterpret_cast<const float4*>(&wt[c*96+o0]);
    *reinterpret_cast<float4*>(&w[4]) = *reinterpret_cast<const float4*>(&wt[c*96+o0+4]);
    #pragma unroll
    for (int oi=0;oi<8;oi++){
      #pragma unroll
      for (int j=0;j<8;j++) acc[oi][j] = fmaf(w[oi], xf[j], acc[oi][j]);
    }
  }
  const u16* y2r = y2 + (size_t)b*48*Sn + soff;
  for (int c=48;c<96;c++){
    uint4 v = *reinterpret_cast<const uint4*>(y2r + (size_t)(c-48)*Sn);
    float xf[8]; unpack8(v, xf);
    float w[8];
    *reinterpret_cast<float4*>(&w[0]) = *reinterpret_cast<const float4*>(&wt[c*96+o0]);
    *reinterpret_cast<float4*>(&w[4]) = *reinterpret_cast<const float4*>(&wt[c*96+o0+4]);
    #pragma unroll
    for (int oi=0;oi<8;oi++){
      #pragma unroll
      for (int j=0;j<8;j++) acc[oi][j] = fmaf(w[oi], xf[j], acc[oi][j]);
    }
  }
  __syncthreads();   // all reads of this s-tile complete before in-place writes
  #pragma unroll
  for (int oi=0;oi<8;oi++){
    size_t off = ((size_t)b*96 + o0 + oi) * Sn + soff;
    float rf[8]; load8f(x + off, rf);
    float ob[8];
    #pragma unroll
    for (int j=0;j<8;j++) ob[j] = acc[oi][j] + rf[j];
    *reinterpret_cast<float4*>(out + off)     = *reinterpret_cast<const float4*>(&ob[0]);
    *reinterpret_cast<float4*>(out + off + 4) = *reinterpret_cast<const float4*>(&ob[4]);
  }
}

extern "C" void kernel_launch(void* const* d_in, const int* in_sizes, int n_in,
                              void* d_out, int out_size, void* d_ws, size_t ws_size,
                              hipStream_t stream){
  const float* x      = (const float*)d_in[0];
  const float* gamma  = (const float*)d_in[1];
  const float* beta   = (const float*)d_in[2];
  const float* in_w   = (const float*)d_in[3];
  const float* in_b   = (const float*)d_in[4];
  const float* ssm_w  = (const float*)d_in[5];
  const float* ssm_b  = (const float*)d_in[6];
  const float* mam_w  = (const float*)d_in[7];
  const float* mam_b  = (const float*)d_in[8];
  const float* sym_w  = (const float*)d_in[9];
  const float* sym_b  = (const float*)d_in[10];
  const float* out_w  = (const float*)d_in[11];
  const float* out_b  = (const float*)d_in[12];
  float* out = (float*)d_out;

  // d_out (201.3 MB fp32) doubles as scratch:
  //   xp fp32 [b][96][Sn]  (written by gemm_in)
  //   t1 bf16 [b][48][Sn]  packed into fp32 words [48*Sn, 96*Sn) = b0 ch48..95 (dead after dw_sym)
  //   y1 fp32 -> ch 0..47  (xp[0:48] dead after dw_ssm)
  u16* t1 = (u16*)d_out + (size_t)96*Sn;    // u16 offset 25,165,824

  char* ws = (char*)d_ws;
  u16*    y2    = (u16*)ws;                                    // 2*48*Sn bf16 = 50331648 B
  float2* psum  = (float2*)(ws + 50331648);                    // 768*8 = 6144 B
  float*  W2t   = (float*)(ws + 50331648 + 6144);              // 2*96*96*4 = 73728 B
  float*  bias2 = (float*)(ws + 50331648 + 6144 + 73728);      // 2*96*4 = 768 B

  // 1) norm stats
  k_stats_partial<<<768, 256, 0, stream>>>(x, psum);
  // 2) finalize + fold norm into in-proj
  k_fold<<<1, 192, 0, stream>>>(psum, gamma, beta, in_w, in_b, W2t, bias2);
  // 3) xp = W2*x + bias2  (fp32, into d_out)
  k_gemm_in<<<4096, 192, 0, stream>>>(x, W2t, bias2, out);
  // 4) y2 = silu(dw_sym(xp[:, 48:]))  -> ws (bf16)
  k_dw<1,1,0><<<6144, 256, 0, stream>>>(out, 96, 48, y2, 48, 0, sym_w, sym_b);
  // 5) t1 = silu(dw_ssm(xp[:, :48])) -> packed bf16 into dead b0-ch48.. region
  k_dw<1,1,0><<<6144, 256, 0, stream>>>(out, 96, 0,  t1, 48, 0, ssm_w, ssm_b);
  // 6) y1 = dw_mamba(t1) -> fp32 into d_out ch 0..47 (xp[0:48] dead)
  k_dw<0,0,1><<<6144, 256, 0, stream>>>(t1, 48, 0,  out, 96, 0, mam_w, mam_b);
  // 7) out = out_w * [y1; y2] + out_b + x   (in-place on d_out, fp32)
  k_gemm_out<<<4096, 192, 0, stream>>>(out, y2, x, out_w, out_b, out);
}

// Round 4
// 438.243 us; speedup vs baseline: 1.7833x; 1.7833x over previous
//
#include <hip/hip_runtime.h>
#include <hip/hip_bf16.h>

using u16 = unsigned short;
using u32 = unsigned int;
typedef __attribute__((ext_vector_type(8))) short bf16x8;
typedef __attribute__((ext_vector_type(4))) float f32x4;

#define DEVFN __device__ __forceinline__

static constexpr int Sn = 64*64*64;          // 262144 spatial per (b,c)
static constexpr float EPS_ = 1e-5f;

DEVFN float lo2f(u32 u){ union { u32 i; float f; } v; v.i = u << 16; return v.f; }
DEVFN float hi2f(u32 u){ union { u32 i; float f; } v; v.i = u & 0xffff0000u; return v.f; }
DEVFN float b2f(u16 u){ union { u32 i; float f; } v; v.i = ((u32)u) << 16; return v.f; }
DEVFN u16 f2b(float f){
  union { float f; u32 i; } v; v.f = f;
  u32 r = v.i + 0x7fffu + ((v.i >> 16) & 1u);
  return (u16)(r >> 16);
}
DEVFN void unpack8(uint4 v, float* f){
  f[0]=lo2f(v.x); f[1]=hi2f(v.x);
  f[2]=lo2f(v.y); f[3]=hi2f(v.y);
  f[4]=lo2f(v.z); f[5]=hi2f(v.z);
  f[6]=lo2f(v.w); f[7]=hi2f(v.w);
}
DEVFN void load8f(const float* p, float* f){
  float4 a = *reinterpret_cast<const float4*>(p);
  float4 b = *reinterpret_cast<const float4*>(p + 4);
  f[0]=a.x; f[1]=a.y; f[2]=a.z; f[3]=a.w;
  f[4]=b.x; f[5]=b.y; f[6]=b.z; f[7]=b.w;
}

// ---------------- stats: partial sums per (b,c, quarter) ----------------
__global__ __launch_bounds__(256) void k_stats_partial(
    const float* __restrict__ x, float2* __restrict__ psum){
  int bid = blockIdx.x;            // 768 = 192 bc * 4 chunks
  int bc = bid >> 2, chunk = bid & 3;
  const float* p = x + (size_t)bc * Sn + (size_t)chunk * (Sn/4);
  float s = 0.f, s2 = 0.f;
  int t = threadIdx.x;
  #pragma unroll 4
  for (int k = 0; k < 32; ++k){
    float f[8]; load8f(p + (size_t)k*2048 + t*8, f);
    #pragma unroll
    for (int j=0;j<8;j++){ s += f[j]; s2 += f[j]*f[j]; }
  }
  #pragma unroll
  for (int off=32; off; off>>=1){ s += __shfl_down(s, off); s2 += __shfl_down(s2, off); }
  __shared__ float rs[4], rs2[4];
  int wid = t >> 6;
  if ((t & 63) == 0){ rs[wid]=s; rs2[wid]=s2; }
  __syncthreads();
  if (t == 0){
    psum[bid] = make_float2(rs[0]+rs[1]+rs[2]+rs[3], rs2[0]+rs2[1]+rs2[2]+rs2[3]);
  }
}

// ---------- finalize stats; emit LDS-ready padded bf16 weight images ----------
__global__ __launch_bounds__(192) void k_fold(
    const float2* __restrict__ psum,
    const float* __restrict__ gamma, const float* __restrict__ beta,
    const float* __restrict__ in_w, const float* __restrict__ in_b,
    const float* __restrict__ out_w,
    u16* __restrict__ W2pad /* [b][96][104] bf16: in_w folded with norm */,
    u16* __restrict__ W3pad /* [96][104] bf16: out_w */,
    float* __restrict__ bias2 /* [b][96] */){
  __shared__ float scl[192], shf[192];
  int t = threadIdx.x;       // 0..191  ~ (b,c) and (b,o)
  {
    float s=0.f, s2=0.f;
    #pragma unroll
    for (int k=0;k<4;k++){ float2 v = psum[t*4+k]; s += v.x; s2 += v.y; }
    float inv = 1.f / (float)Sn;
    float mean = s * inv;
    float var  = s2 * inv - mean*mean;
    int c = t % 96;
    float sc = gamma[c] * rsqrtf(var + EPS_);
    scl[t] = sc;
    shf[t] = beta[c] - mean * sc;
  }
  __syncthreads();
  int b = t / 96, o = t % 96;
  float acc = in_b[o];
  for (int c=0;c<96;c++){
    float w = in_w[o*96 + c];
    int bc = b*96 + c;
    W2pad[(size_t)(b*96 + o)*104 + c] = f2b(w * scl[bc]);
    acc += w * shf[bc];
  }
  bias2[t] = acc;
  if (t < 96){
    for (int c=0;c<96;c++) W3pad[(size_t)t*104 + c] = f2b(out_w[t*96 + c]);
  }
}

// ---------------- MFMA GEMM (both channel mixes) ----------------
// D[o][s] = sum_c W[o][c] * X[c][s]  (+bias, + optional residual)
// MODE 0: gemm_in  — X = x (fp32), out = xp (bf16), bias = bias2[b]
// MODE 1: gemm_out — X = [y1 fp32 planes | y2 bf16], out = fp32 + out_b + residual x
template<int MODE>
__global__ __launch_bounds__(256) void k_gemm(
    const float* __restrict__ srcA,   // MODE0: x ; MODE1: y1 (= out planes c<48)
    const u16*  __restrict__ srcB,    // MODE1: y2 (bf16) ; unused MODE0
    const u16*  __restrict__ Wpad,    // padded bf16 weight image(s)
    const float* __restrict__ bias,
    const float* __restrict__ resid,  // MODE1: x
    u16* __restrict__ dst16,          // MODE0: xp
    float* __restrict__ dst32){       // MODE1: out
  __shared__ __attribute__((aligned(16))) u16 lds[224*104];  // W: rows 0..95, X: rows 96..223
  const int t  = threadIdx.x;
  const int b  = blockIdx.x >> 11;
  const int s0 = (blockIdx.x & 2047) << 7;     // 128-s tile

  // stage W (linear u32 copy of pre-padded image)
  const u16* wsrc = Wpad + (MODE==0 ? (size_t)b*9984 : 0);
  for (int i = t; i < 4992; i += 256)
    ((u32*)lds)[i] = ((const u32*)wsrc)[i];

  // stage X transposed: X_lds[s][c], c-contiguous per row (pad 104)
  u16* X = lds + 9984;
  #pragma unroll
  for (int i=0;i<12;i++){
    int idx = i*256 + t;            // 96 c * 32 q
    int c = idx >> 5, q = idx & 31;
    if (MODE==0 || c < 48){
      const float* g = srcA + ((size_t)(b*96 + c))*Sn + s0 + q;
      #pragma unroll
      for (int j=0;j<4;j++)
        X[(q + 32*j)*104 + c] = f2b(g[32*j]);
    } else {
      const u16* g = srcB + ((size_t)(b*48 + (c-48)))*Sn + s0 + q;
      #pragma unroll
      for (int j=0;j<4;j++)
        X[(q + 32*j)*104 + c] = g[32*j];
    }
  }
  __syncthreads();

  const int w  = t >> 6;          // wave 0..3 -> s sub-tiles {2w, 2w+1}
  const int l  = t & 63;
  const int lc = l & 15, lr = l >> 4;

  f32x4 acc[6][2];
  #pragma unroll
  for (int m=0;m<6;m++)
    #pragma unroll
    for (int nn=0;nn<2;nn++)
      #pragma unroll
      for (int r=0;r<4;r++) acc[m][nn][r] = 0.f;

  #pragma unroll
  for (int kk=0; kk<3; ++kk){
    const int kof = kk*32 + lr*8;
    bf16x8 a[6], xb[2];
    #pragma unroll
    for (int m=0;m<6;m++)
      a[m] = *reinterpret_cast<const bf16x8*>(&lds[(16*m + lc)*104 + kof]);
    #pragma unroll
    for (int nn=0;nn<2;nn++)
      xb[nn] = *reinterpret_cast<const bf16x8*>(&X[(w*32 + nn*16 + lc)*104 + kof]);
    #pragma unroll
    for (int m=0;m<6;m++)
      #pragma unroll
      for (int nn=0;nn<2;nn++)
        acc[m][nn] = __builtin_amdgcn_mfma_f32_16x16x32_bf16(a[m], xb[nn], acc[m][nn], 0, 0, 0);
  }

  // epilogue: D lane map col(s)=l&15, row(o)=4*(l>>4)+r
  #pragma unroll
  for (int m=0;m<6;m++){
    #pragma unroll
    for (int r=0;r<4;r++){
      int o = 16*m + lr*4 + r;
      float bv = bias[(MODE==0 ? b*96 : 0) + o];
      #pragma unroll
      for (int nn=0;nn<2;nn++){
        int s = s0 + w*32 + nn*16 + lc;
        size_t off = ((size_t)(b*96 + o))*Sn + s;
        float v = acc[m][nn][r] + bv;
        if (MODE==0) dst16[off] = f2b(v);
        else         dst32[off] = v + resid[off];
      }
    }
  }
}

// ---------------- depthwise 3x3x3 conv (+ optional SiLU), templated dtypes ----------------
template<int SILU, int IN32, int OUT32>
__global__ __launch_bounds__(256) void k_dw(
    const void* __restrict__ srcv, int sCPB, int sCOff,
    void* __restrict__ dstv, int dCPB, int dCOff,
    const float* __restrict__ wts /* [48][27] */, const float* __restrict__ bias){
  int id = blockIdx.x;                  // 2*48*64 blocks
  int d = id & 63; int c = (id >> 6) % 48; int b = id / (48*64);
  int t = threadIdx.x;
  int h = t >> 2, w0 = (t & 3) * 16;
  float wf[27];
  const float* wp = wts + c*27;
  #pragma unroll
  for (int k=0;k<27;k++) wf[k] = wp[k];
  float acc[16];
  float bv = bias[c];
  #pragma unroll
  for (int j=0;j<16;j++) acc[j] = bv;
  size_t cbase = ((size_t)(b*sCPB + sCOff + c)) * Sn;
  const float* spf = (const float*)srcv + cbase;
  const u16*   sph = (const u16*)srcv + cbase;
  #pragma unroll
  for (int dd=-1; dd<=1; dd++){
    int zd = d + dd; if (zd < 0 || zd > 63) continue;
    #pragma unroll
    for (int dh=-1; dh<=1; dh++){
      int zh = h + dh; if (zh < 0 || zh > 63) continue;
      int roff = zd*4096 + zh*64 + w0;
      float m[16], rl, rr;
      if (IN32){
        const float* row = spf + roff;
        load8f(row, m); load8f(row+8, m+8);
        rl = (w0 > 0)  ? row[-1] : 0.f;
        rr = (w0 < 48) ? row[16] : 0.f;
      } else {
        const u16* row = sph + roff;
        unpack8(*reinterpret_cast<const uint4*>(row), m);
        unpack8(*reinterpret_cast<const uint4*>(row+8), m+8);
        rl = (w0 > 0)  ? b2f(row[-1]) : 0.f;
        rr = (w0 < 48) ? b2f(row[16]) : 0.f;
      }
      const float* wk = &wf[(dd+1)*9 + (dh+1)*3];
      #pragma unroll
      for (int j=0;j<16;j++){
        float L = (j==0)  ? rl : m[j-1];
        float R = (j==15) ? rr : m[j+1];
        acc[j] += wk[0]*L + wk[1]*m[j] + wk[2]*R;
      }
    }
  }
  #pragma unroll
  for (int j=0;j<16;j++){
    float v = acc[j];
    if (SILU) v = v / (1.f + __expf(-v));
    acc[j] = v;
  }
  size_t doffs = ((size_t)(b*dCPB + dCOff + c)) * Sn + d*4096 + h*64 + w0;
  if (OUT32){
    float* dp = (float*)dstv + doffs;
    #pragma unroll
    for (int q=0;q<4;q++)
      *reinterpret_cast<float4*>(dp + q*4) = *reinterpret_cast<const float4*>(&acc[q*4]);
  } else {
    u16 ob[16];
    #pragma unroll
    for (int j=0;j<16;j++) ob[j] = f2b(acc[j]);
    u16* dp = (u16*)dstv + doffs;
    *reinterpret_cast<uint4*>(dp)   = *reinterpret_cast<const uint4*>(&ob[0]);
    *reinterpret_cast<uint4*>(dp+8) = *reinterpret_cast<const uint4*>(&ob[8]);
  }
}

extern "C" void kernel_launch(void* const* d_in, const int* in_sizes, int n_in,
                              void* d_out, int out_size, void* d_ws, size_t ws_size,
                              hipStream_t stream){
  const float* x      = (const float*)d_in[0];
  const float* gamma  = (const float*)d_in[1];
  const float* beta   = (const float*)d_in[2];
  const float* in_w   = (const float*)d_in[3];
  const float* in_b   = (const float*)d_in[4];
  const float* ssm_w  = (const float*)d_in[5];
  const float* ssm_b  = (const float*)d_in[6];
  const float* mam_w  = (const float*)d_in[7];
  const float* mam_b  = (const float*)d_in[8];
  const float* sym_w  = (const float*)d_in[9];
  const float* sym_b  = (const float*)d_in[10];
  const float* out_w  = (const float*)d_in[11];
  const float* out_b  = (const float*)d_in[12];
  float* out = (float*)d_out;

  // d_out (50,331,648 fp32 = 100,663,296 u16 slots) doubles as scratch:
  //   xp  bf16: u16 slots [0, 50331648)                (= fp32 words [0, 25165824))
  //   t1  bf16: u16 slots [75497472, 100663296)        (= fp32 words [37748736, 50331648))
  //   y1  fp32: words (b*96+c)*Sn, c<48  -> [0,12.6M) u [25.2M,37.75M) words
  //   (y1 clobbers only dead xp regions; disjoint from t1 — verified.)
  u16* xp_u16 = (u16*)d_out;
  u16* t1     = (u16*)d_out + 75497472u;

  char* ws = (char*)d_ws;
  u16*    y2    = (u16*)ws;                                   // 50,331,648 B
  float2* psum  = (float2*)(ws + 50331648);                   // 6,144 B
  u16*    W2pad = (u16*)(ws + 50331648 + 6144);               // 2*96*104*2 = 39,936 B
  u16*    W3pad = (u16*)(ws + 50331648 + 6144 + 39936);       // 96*104*2 = 19,968 B
  float*  bias2 = (float*)(ws + 50331648 + 6144 + 39936 + 19968); // 768 B

  // 1) norm stats
  k_stats_partial<<<768, 256, 0, stream>>>(x, psum);
  // 2) finalize + fold norm into in-proj; emit padded bf16 weight images
  k_fold<<<1, 192, 0, stream>>>(psum, gamma, beta, in_w, in_b, out_w, W2pad, W3pad, bias2);
  // 3) xp = W2*x + bias2  (MFMA, bf16 out into d_out)
  k_gemm<0><<<4096, 256, 0, stream>>>(x, nullptr, W2pad, bias2, nullptr, xp_u16, nullptr);
  // 4) y2 = silu(dw_sym(xp[:, 48:]))  -> ws (bf16)
  k_dw<1,0,0><<<6144, 256, 0, stream>>>(xp_u16, 96, 48, y2, 48, 0, sym_w, sym_b);
  // 5) t1 = silu(dw_ssm(xp[:, :48])) -> d_out tail (bf16)
  k_dw<1,0,0><<<6144, 256, 0, stream>>>(xp_u16, 96, 0,  t1, 48, 0, ssm_w, ssm_b);
  // 6) y1 = dw_mamba(t1) -> fp32 into d_out planes c 0..47 per batch (xp dead)
  k_dw<0,0,1><<<6144, 256, 0, stream>>>(t1, 48, 0,  out, 96, 0, mam_w, mam_b);
  // 7) out = out_w * [y1; y2] + out_b + x   (MFMA, in-place on d_out, fp32)
  k_gemm<1><<<4096, 256, 0, stream>>>(out, y2, W3pad, out_b, x, nullptr, out);
}

// Round 6
// 415.241 us; speedup vs baseline: 1.8821x; 1.0554x over previous
//
#include <hip/hip_runtime.h>
#include <hip/hip_bf16.h>

using u16 = unsigned short;
using u32 = unsigned int;
typedef __attribute__((ext_vector_type(8))) short bf16x8;
typedef __attribute__((ext_vector_type(4))) float f32x4;

#define DEVFN __device__ __forceinline__

static constexpr int Sn = 64*64*64;          // 262144 spatial per (b,c)
static constexpr float EPS_ = 1e-5f;

DEVFN float lo2f(u32 u){ union { u32 i; float f; } v; v.i = u << 16; return v.f; }
DEVFN float hi2f(u32 u){ union { u32 i; float f; } v; v.i = u & 0xffff0000u; return v.f; }
DEVFN float b2f(u16 u){ union { u32 i; float f; } v; v.i = ((u32)u) << 16; return v.f; }
DEVFN u16 f2b(float f){
  union { float f; u32 i; } v; v.f = f;
  u32 r = v.i + 0x7fffu + ((v.i >> 16) & 1u);
  return (u16)(r >> 16);
}
DEVFN void unpack8(uint4 v, float* f){
  f[0]=lo2f(v.x); f[1]=hi2f(v.x);
  f[2]=lo2f(v.y); f[3]=hi2f(v.y);
  f[4]=lo2f(v.z); f[5]=hi2f(v.z);
  f[6]=lo2f(v.w); f[7]=hi2f(v.w);
}
DEVFN void load8f(const float* p, float* f){
  float4 a = *reinterpret_cast<const float4*>(p);
  float4 b = *reinterpret_cast<const float4*>(p + 4);
  f[0]=a.x; f[1]=a.y; f[2]=a.z; f[3]=a.w;
  f[4]=b.x; f[5]=b.y; f[6]=b.z; f[7]=b.w;
}

// ---------------- stats: partial sums per (b,c, quarter) ----------------
__global__ __launch_bounds__(256) void k_stats_partial(
    const float* __restrict__ x, float2* __restrict__ psum){
  int bid = blockIdx.x;            // 768 = 192 bc * 4 chunks
  int bc = bid >> 2, chunk = bid & 3;
  const float* p = x + (size_t)bc * Sn + (size_t)chunk * (Sn/4);
  float s = 0.f, s2 = 0.f;
  int t = threadIdx.x;
  #pragma unroll 4
  for (int k = 0; k < 32; ++k){
    float f[8]; load8f(p + (size_t)k*2048 + t*8, f);
    #pragma unroll
    for (int j=0;j<8;j++){ s += f[j]; s2 += f[j]*f[j]; }
  }
  #pragma unroll
  for (int off=32; off; off>>=1){ s += __shfl_down(s, off); s2 += __shfl_down(s2, off); }
  __shared__ float rs[4], rs2[4];
  int wid = t >> 6;
  if ((t & 63) == 0){ rs[wid]=s; rs2[wid]=s2; }
  __syncthreads();
  if (t == 0){
    psum[bid] = make_float2(rs[0]+rs[1]+rs[2]+rs[3], rs2[0]+rs2[1]+rs2[2]+rs2[3]);
  }
}

// ---------- finalize stats; emit XOR-swizzled LDS-ready bf16 weight images ----------
// Image layout: row o (128 u16): value W[o][c] at ((c>>3) ^ (o&7))*8 + (c&7)
__global__ __launch_bounds__(192) void k_fold(
    const float2* __restrict__ psum,
    const float* __restrict__ gamma, const float* __restrict__ beta,
    const float* __restrict__ in_w, const float* __restrict__ in_b,
    const float* __restrict__ out_w,
    u16* __restrict__ W2pad /* [b][96][128] */,
    u16* __restrict__ W3pad /* [96][128] */,
    float* __restrict__ bias2 /* [b][96] */){
  __shared__ float scl[192], shf[192];
  int t = threadIdx.x;       // 0..191  ~ (b,c) and (b,o)
  {
    float s=0.f, s2=0.f;
    #pragma unroll
    for (int k=0;k<4;k++){ float2 v = psum[t*4+k]; s += v.x; s2 += v.y; }
    float inv = 1.f / (float)Sn;
    float mean = s * inv;
    float var  = s2 * inv - mean*mean;
    int c = t % 96;
    float sc = gamma[c] * rsqrtf(var + EPS_);
    scl[t] = sc;
    shf[t] = beta[c] - mean * sc;
  }
  __syncthreads();
  int b = t / 96, o = t % 96;
  float acc = in_b[o];
  for (int c=0;c<96;c++){
    float w = in_w[o*96 + c];
    int bc = b*96 + c;
    W2pad[(size_t)((b*96 + o)*128) + (((c>>3) ^ (o&7))<<3) + (c&7)] = f2b(w * scl[bc]);
    acc += w * shf[bc];
  }
  bias2[t] = acc;
  if (t < 96){
    for (int c=0;c<96;c++)
      W3pad[(size_t)(t*128) + (((c>>3) ^ (t&7))<<3) + (c&7)] = f2b(out_w[t*96 + c]);
  }
}

// ---------------- MFMA GEMM (both channel mixes) ----------------
// D[o][s] = sum_c W[o][c] * X[c][s]  (+bias, + optional residual)
// MODE 0: gemm_in  — X = x (fp32), out = xp (bf16, d_out planes 0..191)
// MODE 1: gemm_out — X = [y1 | y2] (bf16, both in ws), out = fp32 + out_b + resid
template<int MODE>
__global__ __launch_bounds__(256, 2) void k_gemm(
    const float* __restrict__ x32,  // MODE0
    const u16*  __restrict__ y1,    // MODE1: ws, plane b*48+c
    const u16*  __restrict__ y2,    // MODE1: ws, plane b*48+(c-48)
    const u16*  __restrict__ Wpad,
    const float* __restrict__ bias,
    const float* __restrict__ resid,
    u16* __restrict__ dst16,
    float* __restrict__ dst32){
  __shared__ __attribute__((aligned(16))) u16 lds[28672];  // W rows 0..95 (12288), X 128 rows (16384)
  const int t  = threadIdx.x;
  const int b  = blockIdx.x >> 11;
  const int s0 = (blockIdx.x & 2047) << 7;     // 128-s tile

  // stage W: linear uint4 copy of pre-swizzled image
  {
    const uint4* wsrc = reinterpret_cast<const uint4*>(Wpad + (MODE==0 ? (size_t)b*12288 : 0));
    uint4* wdst = reinterpret_cast<uint4*>(lds);
    #pragma unroll
    for (int i=0;i<6;i++) wdst[i*256 + t] = wsrc[i*256 + t];
  }

  // stage X transposed + swizzled: X[s][c] at s*128 + ((c>>3)^(s&7))*8 + (c&7)
  u16* X = lds + 12288;
  #pragma unroll
  for (int it=0; it<3; ++it){
    int task = it*256 + t;            // 64 s-pairs * 12 c-octets
    int sp = task & 63, cblk = task >> 6;
    int s = sp*2;
    u16 rA[8], rB[8];
    #pragma unroll
    for (int j=0;j<8;j++){
      int c = cblk*8 + j;
      if (MODE==0){
        float2 v = *reinterpret_cast<const float2*>(x32 + ((size_t)(b*96+c))*Sn + s0 + s);
        rA[j] = f2b(v.x); rB[j] = f2b(v.y);
      } else {
        const u16* src = (c < 48) ? (y1 + ((size_t)(b*48 + c))*Sn)
                                  : (y2 + ((size_t)(b*48 + (c-48)))*Sn);
        u32 v = *reinterpret_cast<const u32*>(src + s0 + s);
        rA[j] = (u16)v; rB[j] = (u16)(v >> 16);
      }
    }
    *reinterpret_cast<uint4*>(&X[s*128     + ((cblk ^ (s&7))<<3)])     = *reinterpret_cast<const uint4*>(rA);
    *reinterpret_cast<uint4*>(&X[(s+1)*128 + ((cblk ^ ((s+1)&7))<<3)]) = *reinterpret_cast<const uint4*>(rB);
  }
  __syncthreads();

  const int w  = t >> 6;          // wave 0..3 -> s sub-tiles {2w, 2w+1}
  const int l  = t & 63;
  const int lc = l & 15, lr = l >> 4;

  f32x4 acc[6][2];
  #pragma unroll
  for (int m=0;m<6;m++)
    #pragma unroll
    for (int nn=0;nn<2;nn++)
      #pragma unroll
      for (int r=0;r<4;r++) acc[m][nn][r] = 0.f;

  #pragma unroll
  for (int kk=0; kk<3; ++kk){
    const int kb = kk*4 + lr;
    const int xo = ((kb ^ (lc & 7)) << 3);   // same xor for A and B rows (row&7 == lc&7)
    bf16x8 a[6], xb[2];
    #pragma unroll
    for (int m=0;m<6;m++)
      a[m] = *reinterpret_cast<const bf16x8*>(&lds[(16*m + lc)*128 + xo]);
    #pragma unroll
    for (int nn=0;nn<2;nn++)
      xb[nn] = *reinterpret_cast<const bf16x8*>(&X[(w*32 + nn*16 + lc)*128 + xo]);
    #pragma unroll
    for (int m=0;m<6;m++)
      #pragma unroll
      for (int nn=0;nn<2;nn++)
        acc[m][nn] = __builtin_amdgcn_mfma_f32_16x16x32_bf16(a[m], xb[nn], acc[m][nn], 0, 0, 0);
  }

  // epilogue: D lane map col(s)=l&15, row(o)=4*(l>>4)+r
  #pragma unroll
  for (int m=0;m<6;m++){
    #pragma unroll
    for (int r=0;r<4;r++){
      int o = 16*m + lr*4 + r;
      float bv = bias[(MODE==0 ? b*96 : 0) + o];
      #pragma unroll
      for (int nn=0;nn<2;nn++){
        int s = s0 + w*32 + nn*16 + lc;
        size_t off = ((size_t)(b*96 + o))*Sn + s;
        float v = acc[m][nn][r] + bv;
        if (MODE==0) dst16[off] = f2b(v);
        else         dst32[off] = v + resid[off];
      }
    }
  }
}

// ---------------- depthwise 3x3x3 conv (+ optional SiLU), bf16 in/out ----------------
template<int SILU>
__global__ __launch_bounds__(256) void k_dw(
    const u16* __restrict__ src, int sCPB, int sCOff,
    u16* __restrict__ dst, int dCPB, int dCOff,
    const float* __restrict__ wts /* [48][27] */, const float* __restrict__ bias){
  int hw = blockIdx.x;                  // 6144 blocks; XCD-chunked swizzle:
  int id = (hw & 7)*768 + (hw >> 3);    // all 64 d of a (b,c) column on one XCD
  int d = id & 63; int c = (id >> 6) % 48; int b = id / (48*64);
  int t = threadIdx.x;
  int h = t >> 2, w0 = (t & 3) * 16;
  float wf[27];
  const float* wp = wts + c*27;
  #pragma unroll
  for (int k=0;k<27;k++) wf[k] = wp[k];
  float acc[16];
  float bv = bias[c];
  #pragma unroll
  for (int j=0;j<16;j++) acc[j] = bv;
  const u16* sp = src + ((size_t)(b*sCPB + sCOff + c)) * Sn;
  #pragma unroll
  for (int dd=-1; dd<=1; dd++){
    int zd = d + dd; if (zd < 0 || zd > 63) continue;
    #pragma unroll
    for (int dh=-1; dh<=1; dh++){
      int zh = h + dh; if (zh < 0 || zh > 63) continue;
      const u16* row = sp + zd*4096 + zh*64 + w0;
      float m[16];
      unpack8(*reinterpret_cast<const uint4*>(row), m);
      unpack8(*reinterpret_cast<const uint4*>(row+8), m+8);
      float rl = (w0 > 0)  ? b2f(row[-1]) : 0.f;
      float rr = (w0 < 48) ? b2f(row[16]) : 0.f;
      const float* wk = &wf[(dd+1)*9 + (dh+1)*3];
      #pragma unroll
      for (int j=0;j<16;j++){
        float L = (j==0)  ? rl : m[j-1];
        float R = (j==15) ? rr : m[j+1];
        acc[j] += wk[0]*L + wk[1]*m[j] + wk[2]*R;
      }
    }
  }
  u16 ob[16];
  #pragma unroll
  for (int j=0;j<16;j++){
    float v = acc[j];
    if (SILU) v = v / (1.f + __expf(-v));
    ob[j] = f2b(v);
  }
  u16* dp = dst + ((size_t)(b*dCPB + dCOff + c)) * Sn + d*4096 + h*64 + w0;
  *reinterpret_cast<uint4*>(dp)   = *reinterpret_cast<const uint4*>(&ob[0]);
  *reinterpret_cast<uint4*>(dp+8) = *reinterpret_cast<const uint4*>(&ob[8]);
}

extern "C" void kernel_launch(void* const* d_in, const int* in_sizes, int n_in,
                              void* d_out, int out_size, void* d_ws, size_t ws_size,
                              hipStream_t stream){
  const float* x      = (const float*)d_in[0];
  const float* gamma  = (const float*)d_in[1];
  const float* beta   = (const float*)d_in[2];
  const float* in_w   = (const float*)d_in[3];
  const float* in_b   = (const float*)d_in[4];
  const float* ssm_w  = (const float*)d_in[5];
  const float* ssm_b  = (const float*)d_in[6];
  const float* mam_w  = (const float*)d_in[7];
  const float* mam_b  = (const float*)d_in[8];
  const float* sym_w  = (const float*)d_in[9];
  const float* sym_b  = (const float*)d_in[10];
  const float* out_w  = (const float*)d_in[11];
  const float* out_b  = (const float*)d_in[12];
  float* out = (float*)d_out;

  // d_out = 384 u16-planes (each Sn u16), used as scratch only BEFORE gemm_out:
  //   xp bf16: planes 0..191  (b*96 + c)
  //   t1 bf16: planes 192..335 (b*96 + 192 + c)  — disjoint from xp
  // gemm_out reads NOTHING from d_out (y1/y2 in ws) -> no in-place hazard.
  u16* du16 = (u16*)d_out;

  char* ws = (char*)d_ws;   // ws_size ≈ 768 MiB (harness poison-fill evidence); we use 75.6 MB
  u16*    y2    = (u16*)ws;                                    // 50,331,648 B
  u16*    y1    = (u16*)(ws + 50331648);                       // 25,165,824 B
  float2* psum  = (float2*)(ws + 75497472);                    // 6,144 B
  u16*    W2pad = (u16*)(ws + 75497472 + 6144);                // 49,152 B
  u16*    W3pad = (u16*)(ws + 75497472 + 6144 + 49152);        // 24,576 B
  float*  bias2 = (float*)(ws + 75497472 + 6144 + 49152 + 24576); // 768 B

  // 1) norm stats
  k_stats_partial<<<768, 256, 0, stream>>>(x, psum);
  // 2) finalize + fold norm into in-proj; emit swizzled bf16 weight images
  k_fold<<<1, 192, 0, stream>>>(psum, gamma, beta, in_w, in_b, out_w, W2pad, W3pad, bias2);
  // 3) xp = W2*x + bias2  (MFMA, bf16 into d_out planes 0..191)
  k_gemm<0><<<4096, 256, 0, stream>>>(x, nullptr, nullptr, W2pad, bias2, nullptr, du16, nullptr);
  // 4) y2 = silu(dw_sym(xp[:, 48:]))  -> ws
  k_dw<1><<<6144, 256, 0, stream>>>(du16, 96, 48, y2, 48, 0, sym_w, sym_b);
  // 5) t1 = silu(dw_ssm(xp[:, :48])) -> d_out planes 192..335
  k_dw<1><<<6144, 256, 0, stream>>>(du16, 96, 0,  du16, 96, 192, ssm_w, ssm_b);
  // 6) y1 = dw_mamba(t1) -> ws (bf16)
  k_dw<0><<<6144, 256, 0, stream>>>(du16, 96, 192, y1, 48, 0, mam_w, mam_b);
  // 7) out = out_w * [y1; y2] + out_b + x   (MFMA, fp32 into d_out; reads only ws + x)
  k_gemm<1><<<4096, 256, 0, stream>>>(nullptr, y1, y2, W3pad, out_b, x, nullptr, out);
}

// Round 8
// 360.841 us; speedup vs baseline: 2.1658x; 1.1508x over previous
//
#include <hip/hip_runtime.h>
#include <hip/hip_bf16.h>

using u16 = unsigned short;
using u32 = unsigned int;
typedef __attribute__((ext_vector_type(8))) short bf16x8;
typedef __attribute__((ext_vector_type(4))) float f32x4;

#define DEVFN __device__ __forceinline__

static constexpr int Sn = 64*64*64;          // 262144 spatial per (b,c)
static constexpr float EPS_ = 1e-5f;

DEVFN float lo2f(u32 u){ union { u32 i; float f; } v; v.i = u << 16; return v.f; }
DEVFN float hi2f(u32 u){ union { u32 i; float f; } v; v.i = u & 0xffff0000u; return v.f; }
DEVFN float b2f(u16 u){ union { u32 i; float f; } v; v.i = ((u32)u) << 16; return v.f; }
DEVFN u16 f2b(float f){
  union { float f; u32 i; } v; v.f = f;
  u32 r = v.i + 0x7fffu + ((v.i >> 16) & 1u);
  return (u16)(r >> 16);
}
DEVFN void unpack8(uint4 v, float* f){
  f[0]=lo2f(v.x); f[1]=hi2f(v.x);
  f[2]=lo2f(v.y); f[3]=hi2f(v.y);
  f[4]=lo2f(v.z); f[5]=hi2f(v.z);
  f[6]=lo2f(v.w); f[7]=hi2f(v.w);
}
DEVFN void load8f(const float* p, float* f){
  float4 a = *reinterpret_cast<const float4*>(p);
  float4 b = *reinterpret_cast<const float4*>(p + 4);
  f[0]=a.x; f[1]=a.y; f[2]=a.z; f[3]=a.w;
  f[4]=b.x; f[5]=b.y; f[6]=b.z; f[7]=b.w;
}

// ---------------- stats: partial sums per (b,c, quarter) ----------------
__global__ __launch_bounds__(256) void k_stats_partial(
    const float* __restrict__ x, float2* __restrict__ psum){
  int bid = blockIdx.x;            // 768 = 192 bc * 4 chunks
  int bc = bid >> 2, chunk = bid & 3;
  const float* p = x + (size_t)bc * Sn + (size_t)chunk * (Sn/4);
  float s = 0.f, s2 = 0.f;
  int t = threadIdx.x;
  #pragma unroll 4
  for (int k = 0; k < 32; ++k){
    float f[8]; load8f(p + (size_t)k*2048 + t*8, f);
    #pragma unroll
    for (int j=0;j<8;j++){ s += f[j]; s2 += f[j]*f[j]; }
  }
  #pragma unroll
  for (int off=32; off; off>>=1){ s += __shfl_down(s, off); s2 += __shfl_down(s2, off); }
  __shared__ float rs[4], rs2[4];
  int wid = t >> 6;
  if ((t & 63) == 0){ rs[wid]=s; rs2[wid]=s2; }
  __syncthreads();
  if (t == 0){
    psum[bid] = make_float2(rs[0]+rs[1]+rs[2]+rs[3], rs2[0]+rs2[1]+rs2[2]+rs2[3]);
  }
}

// ---------- finalize stats; emit LDS-ready [96][104] bf16 weight images ----------
__global__ __launch_bounds__(192) void k_fold(
    const float2* __restrict__ psum,
    const float* __restrict__ gamma, const float* __restrict__ beta,
    const float* __restrict__ in_w, const float* __restrict__ in_b,
    const float* __restrict__ out_w,
    u16* __restrict__ W2pad /* [b][96][104] */,
    u16* __restrict__ W3pad /* [96][104] */,
    float* __restrict__ bias2 /* [b][96] */){
  __shared__ float scl[192], shf[192];
  int t = threadIdx.x;       // 0..191  ~ (b,c) and (b,o)
  {
    float s=0.f, s2=0.f;
    #pragma unroll
    for (int k=0;k<4;k++){ float2 v = psum[t*4+k]; s += v.x; s2 += v.y; }
    float inv = 1.f / (float)Sn;
    float mean = s * inv;
    float var  = s2 * inv - mean*mean;
    int c = t % 96;
    float sc = gamma[c] * rsqrtf(var + EPS_);
    scl[t] = sc;
    shf[t] = beta[c] - mean * sc;
  }
  __syncthreads();
  int b = t / 96, o = t % 96;
  float acc = in_b[o];
  for (int c=0;c<96;c++){
    float w = in_w[o*96 + c];
    int bc = b*96 + c;
    W2pad[(size_t)(b*96 + o)*104 + c] = f2b(w * scl[bc]);
    acc += w * shf[bc];
  }
  bias2[t] = acc;
  if (t < 96){
    for (int c=0;c<96;c++)
      W3pad[(size_t)t*104 + c] = f2b(out_w[t*96 + c]);
  }
}

// ---------------- MFMA GEMM (both channel mixes) ----------------
// D[o][s] = sum_c W[o][c] * X[c][s]  (+bias, + optional residual)
// Tile: 96 o x 64 s, 4 waves (each 96o x 16s). 8192 blocks.
// MODE 0: gemm_in  — X = x (fp32), out = xp (bf16)
// MODE 1: gemm_out — X = [y1 | y2] (bf16 in ws), out = fp32 + out_b + resid
template<int MODE>
__global__ __launch_bounds__(256, 4) void k_gemm(
    const float* __restrict__ x32,  // MODE0
    const u16*  __restrict__ y1,    // MODE1: ws, plane b*48+c
    const u16*  __restrict__ y2,    // MODE1: ws, plane b*48+(c-48)
    const u16*  __restrict__ Wpad,  // [96][104] images
    const float* __restrict__ bias,
    const float* __restrict__ resid,
    u16* __restrict__ dst16,
    float* __restrict__ dst32){
  __shared__ __attribute__((aligned(16))) u16 lds[18432];  // 36864 B
  u16* Wl = lds;           // [96][104] = 9984 u16 (19968 B = 1248 uint4)
  u16* X  = lds + 9984;    // [64][132] = 8448 u16
  const int t  = threadIdx.x;
  const int b  = blockIdx.x >> 12;
  const int s0 = (blockIdx.x & 4095) << 6;     // 64-s tile

  // stage W: linear uint4 copy (1248 uint4 = 9984 u16)
  {
    const uint4* wsrc = reinterpret_cast<const uint4*>(Wpad + (MODE==0 ? (size_t)b*9984 : 0));
    uint4* wdst = reinterpret_cast<uint4*>(lds);
    #pragma unroll
    for (int i=0;i<5;i++){ int idx = i*256 + t; if (idx < 1248) wdst[idx] = wsrc[idx]; }
  }

  // stage X transposed: X[s][c] plain layout, stride 132 (bank-spread by stride)
  #pragma unroll
  for (int it=0; it<2; ++it){
    int task = it*256 + t;                // 384 tasks = 32 s-pairs x 12 c-octets
    if (task < 384){
      int sp = task & 31, cblk = task >> 5;
      int s = sp*2;
      u16 rA[8], rB[8];
      #pragma unroll
      for (int j=0;j<8;j++){
        int c = cblk*8 + j;
        if (MODE==0){
          float2 v = *reinterpret_cast<const float2*>(x32 + ((size_t)(b*96+c))*Sn + s0 + s);
          rA[j] = f2b(v.x); rB[j] = f2b(v.y);
        } else {
          const u16* src = (c < 48) ? (y1 + ((size_t)(b*48 + c))*Sn)
                                    : (y2 + ((size_t)(b*48 + (c-48)))*Sn);
          u32 v = *reinterpret_cast<const u32*>(src + s0 + s);
          rA[j] = (u16)v; rB[j] = (u16)(v >> 16);
        }
      }
      // even row: 16B aligned -> uint4; odd row: 8B aligned -> 2x uint2
      *reinterpret_cast<uint4*>(&X[(size_t)s*132 + cblk*8]) = *reinterpret_cast<const uint4*>(rA);
      *reinterpret_cast<uint2*>(&X[(size_t)(s+1)*132 + cblk*8])     = *reinterpret_cast<const uint2*>(&rB[0]);
      *reinterpret_cast<uint2*>(&X[(size_t)(s+1)*132 + cblk*8 + 4]) = *reinterpret_cast<const uint2*>(&rB[4]);
    }
  }
  __syncthreads();

  const int w  = t >> 6;          // wave 0..3 -> s sub-tile [w*16, w*16+16)
  const int l  = t & 63;
  const int lc = l & 15, lr = l >> 4;

  f32x4 acc[6];
  #pragma unroll
  for (int m=0;m<6;m++)
    #pragma unroll
    for (int r=0;r<4;r++) acc[m][r] = 0.f;

  #pragma unroll
  for (int kk=0; kk<3; ++kk){
    const int kb = kk*4 + lr;     // k-octet
    bf16x8 xb;
    {
      const u16* px = &X[(size_t)(w*16 + lc)*132 + kb*8];
      uint2 p0 = *reinterpret_cast<const uint2*>(px);
      uint2 p1 = *reinterpret_cast<const uint2*>(px + 4);
      union { uint4 u; bf16x8 v; } cv;
      cv.u = make_uint4(p0.x, p0.y, p1.x, p1.y);
      xb = cv.v;
    }
    #pragma unroll
    for (int m=0;m<6;m++){
      bf16x8 a = *reinterpret_cast<const bf16x8*>(&Wl[(size_t)(16*m + lc)*104 + kb*8]);
      acc[m] = __builtin_amdgcn_mfma_f32_16x16x32_bf16(a, xb, acc[m], 0, 0, 0);
    }
  }
  __syncthreads();   // all LDS reads done; reuse LDS for epilogue staging

  if (MODE==0){
    u16* eps = lds;              // [96][72]
    #pragma unroll
    for (int m=0;m<6;m++){
      #pragma unroll
      for (int r=0;r<4;r++){
        int o = 16*m + lr*4 + r;
        eps[(size_t)o*72 + w*16 + lc] = f2b(acc[m][r] + bias[b*96 + o]);
      }
    }
    __syncthreads();
    #pragma unroll
    for (int i=0;i<3;i++){
      int idx = i*256 + t;       // 768 = 96 o x 8 octets
      int o = idx >> 3, qq = idx & 7;
      *reinterpret_cast<uint4*>(dst16 + ((size_t)(b*96 + o))*Sn + s0 + qq*8) =
          *reinterpret_cast<const uint4*>(&eps[(size_t)o*72 + qq*8]);
    }
  } else {
    float* eps = reinterpret_cast<float*>(lds);   // [96][68] f32 = 26112 B
    #pragma unroll
    for (int m=0;m<6;m++){
      #pragma unroll
      for (int r=0;r<4;r++){
        int o = 16*m + lr*4 + r;
        eps[(size_t)o*68 + w*16 + lc] = acc[m][r] + bias[o];
      }
    }
    __syncthreads();
    #pragma unroll
    for (int i=0;i<6;i++){
      int idx = i*256 + t;       // 1536 = 96 o x 16 quads
      int o = idx >> 4, qq = idx & 15;
      size_t off = ((size_t)(b*96 + o))*Sn + s0 + qq*4;
      float4 v  = *reinterpret_cast<const float4*>(&eps[(size_t)o*68 + qq*4]);
      float4 rr = *reinterpret_cast<const float4*>(resid + off);
      v.x += rr.x; v.y += rr.y; v.z += rr.z; v.w += rr.w;
      *reinterpret_cast<float4*>(dst32 + off) = v;
    }
  }
}

// ---------------- depthwise 3x3x3 conv (+ optional SiLU), bf16 in/out ----------------
template<int SILU>
__global__ __launch_bounds__(256) void k_dw(
    const u16* __restrict__ src, int sCPB, int sCOff,
    u16* __restrict__ dst, int dCPB, int dCOff,
    const float* __restrict__ wts /* [48][27] */, const float* __restrict__ bias){
  int hw = blockIdx.x;                  // 6144 blocks; XCD-chunked swizzle:
  int id = (hw & 7)*768 + (hw >> 3);    // all 64 d of a (b,c) column on one XCD
  int d = id & 63; int c = (id >> 6) % 48; int b = id / (48*64);
  int t = threadIdx.x;
  int h = t >> 2, w0 = (t & 3) * 16;
  float wf[27];
  const float* wp = wts + c*27;
  #pragma unroll
  for (int k=0;k<27;k++) wf[k] = wp[k];
  float acc[16];
  float bv = bias[c];
  #pragma unroll
  for (int j=0;j<16;j++) acc[j] = bv;
  const u16* sp = src + ((size_t)(b*sCPB + sCOff + c)) * Sn;
  #pragma unroll
  for (int dd=-1; dd<=1; dd++){
    int zd = d + dd; if (zd < 0 || zd > 63) continue;
    #pragma unroll
    for (int dh=-1; dh<=1; dh++){
      int zh = h + dh; if (zh < 0 || zh > 63) continue;
      const u16* row = sp + zd*4096 + zh*64 + w0;
      float m[16];
      unpack8(*reinterpret_cast<const uint4*>(row), m);
      unpack8(*reinterpret_cast<const uint4*>(row+8), m+8);
      // row edges via wave shuffle: w=64 row spans exactly 4 lanes
      float rl = __shfl_up(m[15], 1);
      float rr = __shfl_down(m[0], 1);
      if ((t & 3) == 0) rl = 0.f;
      if ((t & 3) == 3) rr = 0.f;
      const float* wk = &wf[(dd+1)*9 + (dh+1)*3];
      #pragma unroll
      for (int j=0;j<16;j++){
        float L = (j==0)  ? rl : m[j-1];
        float R = (j==15) ? rr : m[j+1];
        acc[j] += wk[0]*L + wk[1]*m[j] + wk[2]*R;
      }
    }
  }
  u16 ob[16];
  #pragma unroll
  for (int j=0;j<16;j++){
    float v = acc[j];
    if (SILU) v = v / (1.f + __expf(-v));
    ob[j] = f2b(v);
  }
  u16* dp = dst + ((size_t)(b*dCPB + dCOff + c)) * Sn + d*4096 + h*64 + w0;
  *reinterpret_cast<uint4*>(dp)   = *reinterpret_cast<const uint4*>(&ob[0]);
  *reinterpret_cast<uint4*>(dp+8) = *reinterpret_cast<const uint4*>(&ob[8]);
}

extern "C" void kernel_launch(void* const* d_in, const int* in_sizes, int n_in,
                              void* d_out, int out_size, void* d_ws, size_t ws_size,
                              hipStream_t stream){
  const float* x      = (const float*)d_in[0];
  const float* gamma  = (const float*)d_in[1];
  const float* beta   = (const float*)d_in[2];
  const float* in_w   = (const float*)d_in[3];
  const float* in_b   = (const float*)d_in[4];
  const float* ssm_w  = (const float*)d_in[5];
  const float* ssm_b  = (const float*)d_in[6];
  const float* mam_w  = (const float*)d_in[7];
  const float* mam_b  = (const float*)d_in[8];
  const float* sym_w  = (const float*)d_in[9];
  const float* sym_b  = (const float*)d_in[10];
  const float* out_w  = (const float*)d_in[11];
  const float* out_b  = (const float*)d_in[12];
  float* out = (float*)d_out;

  // d_out = 384 u16-planes (each Sn u16), scratch only BEFORE gemm_out:
  //   xp bf16: planes 0..191 ; t1 bf16: planes 192..335 (disjoint)
  // gemm_out reads nothing from d_out -> no in-place hazard.
  u16* du16 = (u16*)d_out;

  char* ws = (char*)d_ws;
  u16*    y2    = (u16*)ws;                                    // 50,331,648 B
  u16*    y1    = (u16*)(ws + 50331648);                       // 25,165,824 B
  float2* psum  = (float2*)(ws + 75497472);                    // 6,144 B
  u16*    W2pad = (u16*)(ws + 75497472 + 6144);                // 2*96*104*2 = 39,936 B
  u16*    W3pad = (u16*)(ws + 75497472 + 6144 + 39936);        // 96*104*2 = 19,968 B
  float*  bias2 = (float*)(ws + 75497472 + 6144 + 39936 + 19968); // 768 B

  // 1) norm stats
  k_stats_partial<<<768, 256, 0, stream>>>(x, psum);
  // 2) finalize + fold norm into in-proj; emit [96][104] bf16 weight images
  k_fold<<<1, 192, 0, stream>>>(psum, gamma, beta, in_w, in_b, out_w, W2pad, W3pad, bias2);
  // 3) xp = W2*x + bias2  (MFMA, bf16 into d_out planes 0..191)
  k_gemm<0><<<8192, 256, 0, stream>>>(x, nullptr, nullptr, W2pad, bias2, nullptr, du16, nullptr);
  // 4) y2 = silu(dw_sym(xp[:, 48:]))  -> ws
  k_dw<1><<<6144, 256, 0, stream>>>(du16, 96, 48, y2, 48, 0, sym_w, sym_b);
  // 5) t1 = silu(dw_ssm(xp[:, :48])) -> d_out planes 192..335
  k_dw<1><<<6144, 256, 0, stream>>>(du16, 96, 0,  du16, 96, 192, ssm_w, ssm_b);
  // 6) y1 = dw_mamba(t1) -> ws (bf16)
  k_dw<0><<<6144, 256, 0, stream>>>(du16, 96, 192, y1, 48, 0, mam_w, mam_b);
  // 7) out = out_w * [y1; y2] + out_b + x   (MFMA, fp32 into d_out; reads only ws + x)
  k_gemm<1><<<8192, 256, 0, stream>>>(nullptr, y1, y2, W3pad, out_b, x, nullptr, out);
}